// Round 4
// baseline (247.982 us; speedup 1.0000x reference)
//
#include <hip/hip_runtime.h>

typedef unsigned int uint;
typedef unsigned short ushort;
typedef __attribute__((ext_vector_type(4))) float f32x4;
typedef __attribute__((ext_vector_type(4))) uint u32x4;
typedef __attribute__((ext_vector_type(2))) uint u32x2;

#define NNODES 100000
#define NPAD   100032          // NNODES rounded to 64
#define NEDGES 1600000
#define FD 128
#define BM 64
#define NCHUNK 8               // 8 feature chunks of 16 -> one per XCD
#define CHELEM (NPAD * 16)     // ushorts per chunk (3.2 MB)

// round-to-nearest-even f32 -> bf16 (scalar)
__device__ __forceinline__ ushort f2bf(float f) {
    uint u = __float_as_uint(f);
    u += 0x7fffu + ((u >> 16) & 1u);
    return (ushort)(u >> 16);
}
// packed f32x2 -> bf16x2 (RNE), lo -> bits[15:0]
__device__ __forceinline__ uint cvt_pk_bf16(float lo, float hi) {
    uint r;
    asm("v_cvt_pk_bf16_f32 %0, %1, %2" : "=v"(r) : "v"(lo), "v"(hi));
    return r;
}
// swizzled byte offset in a [rows][128] bf16 LDS tile (T2)
__device__ __forceinline__ int swz(int row, int k) {
    return (row * 256 + k * 2) ^ ((row & 7) << 4);
}
__device__ __forceinline__ float bflo(uint s) { return __uint_as_float(s << 16); }
__device__ __forceinline__ float bfhi(uint s) { return __uint_as_float(s & 0xffff0000u); }

// ---------------------------------------------------------------------------
// Pre-kernel: Wt[n][k] = bf16(W[k][n]), PRE-SWIZZLED for flat LDS staging.
// ---------------------------------------------------------------------------
__global__ __launch_bounds__(256) void build_wt(const float* __restrict__ W,
                                                ushort* __restrict__ Wt) {
    const int sid = blockIdx.x * 256 + threadIdx.x;   // 4096 slots
    const int n = sid & 127, k0 = (sid >> 7) * 4;
    const float w0 = W[(k0 + 0) * FD + n];
    const float w1 = W[(k0 + 1) * FD + n];
    const float w2 = W[(k0 + 2) * FD + n];
    const float w3 = W[(k0 + 3) * FD + n];
    u32x2 p;
    p.x = cvt_pk_bf16(w0, w1);
    p.y = cvt_pk_bf16(w2, w3);
    *(u32x2*)((char*)Wt + swz(n, k0)) = p;
}

// ---------------------------------------------------------------------------
// row_ptr[r] = lower_bound(edge_row, r)
// ---------------------------------------------------------------------------
__global__ __launch_bounds__(256) void build_rowptr(const int* __restrict__ rows,
                                                    int* __restrict__ ptr) {
    const int r = blockIdx.x * 256 + threadIdx.x;
    if (r > NNODES) return;
    int lo = 0, hi = NEDGES;
    while (lo < hi) {
        const int mid = (lo + hi) >> 1;
        const bool lt = rows[mid] < r;
        lo = lt ? mid + 1 : lo;
        hi = lt ? hi : mid;
    }
    ptr[r] = lo;
}

// ---------------------------------------------------------------------------
// GEMM: S = bf16(X @ W), stored CHUNK-MAJOR: S[chunk][node][16].
// 64x128 tile/block, 4 waves, 16x16x32 bf16 MFMA (inline asm), swizzled LDS.
// ---------------------------------------------------------------------------
__global__ __launch_bounds__(256) void gemm_mfma(const float* __restrict__ X,
                                                 const ushort* __restrict__ Wt,
                                                 ushort* __restrict__ S) {
    __shared__ ushort As[BM * FD];   // 16 KB, swizzled
    __shared__ ushort Bs[FD * FD];   // 32 KB, swizzled (flat copy of Wt)
    const int tid = threadIdx.x;
    const int row0 = blockIdx.x * BM;

    #pragma unroll
    for (int it = 0; it < 8; ++it) {
        const int idx = tid + it * 256;            // [0,2048)
        const int r = idx >> 5, k0 = (idx & 31) * 4;
        const int grow = min(row0 + r, NNODES - 1);
        const float4 g = *(const float4*)&X[grow * FD + k0];
        u32x2 p;
        p.x = cvt_pk_bf16(g.x, g.y);
        p.y = cvt_pk_bf16(g.z, g.w);
        *(u32x2*)((char*)As + swz(r, k0)) = p;
    }
    #pragma unroll
    for (int it = 0; it < 8; ++it) {
        const int b = (tid + it * 256) * 16;
        *(u32x4*)((char*)Bs + b) = *(const u32x4*)((const char*)Wt + b);
    }
    __syncthreads();

    const int lane = tid & 63, wv = tid >> 6;
    const int l15 = lane & 15, kg = lane >> 4;
    const int arow = wv * 16 + l15;

    f32x4 acc[8];
    #pragma unroll
    for (int i = 0; i < 8; ++i) acc[i] = (f32x4)0.f;

    #pragma unroll
    for (int ks = 0; ks < 4; ++ks) {
        const int k0 = ks * 32 + kg * 8;
        const u32x4 a = *(const u32x4*)((const char*)As + swz(arow, k0));
        #pragma unroll
        for (int nf = 0; nf < 8; ++nf) {
            const u32x4 b = *(const u32x4*)((const char*)Bs + swz(nf * 16 + l15, k0));
            asm volatile("v_mfma_f32_16x16x32_bf16 %0, %1, %2, %0"
                         : "+v"(acc[nf]) : "v"(a), "v"(b));
        }
    }
    asm volatile("s_nop 7\ns_nop 7\ns_nop 7");   // MFMA -> VALU hazard guard

    // chunk-major store: fragment nf covers cols [16nf,16nf+16) == chunk nf
    #pragma unroll
    for (int nf = 0; nf < 8; ++nf) {
        #pragma unroll
        for (int r = 0; r < 4; ++r) {
            const int grow = row0 + wv * 16 + kg * 4 + r;   // C/D row map
            S[nf * CHELEM + grow * 16 + l15] = f2bf(acc[nf][r]);
        }
    }
}

// ---------------------------------------------------------------------------
// SpMM, XCD-partitioned by feature chunk. chunk = blockIdx & 7 -> pinned to
// one XCD (round-robin dispatch), whose L2 holds that 3.2 MB S-slice.
// Wave = one row: 8 edge slots x 8 lanes (lane owns 2 features of 16).
// 16 edges in flight per trip; shfl_xor slot-reduce; 64B/row store per XCD.
// ---------------------------------------------------------------------------
__global__ __launch_bounds__(256) void spmm_chunk(const int* __restrict__ ptr,
                                                  const int* __restrict__ cols,
                                                  const float* __restrict__ vals,
                                                  const ushort* __restrict__ S,
                                                  const float* __restrict__ bias,
                                                  float* __restrict__ out) {
    const int bx = blockIdx.x;
    const int chunk = bx & 7;
    const int row = (bx >> 3) * 4 + (threadIdx.x >> 6);
    const int lane = threadIdx.x & 63;
    const int slot = lane >> 3;        // edge slot 0..7
    const int fl = lane & 7;           // feature-pair 0..7 within chunk

    const int e0 = ptr[row];
    const int e1 = ptr[row + 1];
    const ushort* __restrict__ Sc = S + (size_t)chunk * CHELEM;

    float ax = 0.f, ay = 0.f, bx2 = 0.f, by2 = 0.f;

    for (int e = e0; e < e1; e += 16) {
        int i0 = e + slot;
        int i1 = e + 8 + slot;
        const bool ok0 = i0 < e1, ok1 = i1 < e1;
        i0 = min(i0, e1 - 1);
        i1 = min(i1, e1 - 1);
        const int c0 = cols[i0];
        const int c1 = cols[i1];
        const float v0 = ok0 ? vals[i0] : 0.f;
        const float v1 = ok1 ? vals[i1] : 0.f;
        const uint s0 = *(const uint*)&Sc[c0 * 16 + fl * 2];
        const uint s1 = *(const uint*)&Sc[c1 * 16 + fl * 2];
        ax  = fmaf(v0, bflo(s0), ax);
        ay  = fmaf(v0, bfhi(s0), ay);
        bx2 = fmaf(v1, bflo(s1), bx2);
        by2 = fmaf(v1, bfhi(s1), by2);
    }
    ax += bx2;
    ay += by2;

    #pragma unroll
    for (int m = 8; m < 64; m <<= 1) {
        ax += __shfl_xor(ax, m);
        ay += __shfl_xor(ay, m);
    }

    if (lane < 8) {                    // slot 0 writes: 8 lanes x 8B = 64B line
        const int f = chunk * 16 + fl * 2;
        const float2 bi = *(const float2*)&bias[f];
        float2 o;
        o.x = ax + bi.x;
        o.y = ay + bi.y;
        *(float2*)&out[row * FD + f] = o;
    }
}

// ---------------------------------------------------------------------------
extern "C" void kernel_launch(void* const* d_in, const int* in_sizes, int n_in,
                              void* d_out, int out_size, void* d_ws, size_t ws_size,
                              hipStream_t stream) {
    const float* X    = (const float*)d_in[0];
    const int*   erow = (const int*)d_in[1];
    const int*   ecol = (const int*)d_in[2];
    const float* eval_= (const float*)d_in[3];
    const float* W    = (const float*)d_in[4];
    const float* bias = (const float*)d_in[5];
    float* out = (float*)d_out;

    ushort* S   = (ushort*)d_ws;                               // 25.6 MB chunk-major
    ushort* Wt  = (ushort*)((char*)d_ws + 26u * 1024 * 1024);  // 32 KB
    int*    rpt = (int*)((char*)d_ws + 28u * 1024 * 1024);     // 100001 ints

    build_wt<<<16, 256, 0, stream>>>(W, Wt);
    build_rowptr<<<(NNODES + 256) / 256, 256, 0, stream>>>(erow, rpt);
    gemm_mfma<<<NPAD / BM, 256, 0, stream>>>(X, Wt, S);        // 1563 blocks
    spmm_chunk<<<(NNODES / 4) * NCHUNK, 256, 0, stream>>>(rpt, ecol, eval_, S, bias, out);
}

// Round 5
// 123.812 us; speedup vs baseline: 2.0029x; 2.0029x over previous
//
#include <hip/hip_runtime.h>

typedef unsigned int uint;
typedef unsigned short ushort;
typedef unsigned char uchar;
typedef __attribute__((ext_vector_type(4))) float f32x4;
typedef __attribute__((ext_vector_type(4))) uint u32x4;
typedef __attribute__((ext_vector_type(2))) uint u32x2;

#define NNODES 100000
#define NPAD   100032          // NNODES rounded to 64
#define NEDGES 1600000
#define FD 128
#define BM 64
#define RPW 8                  // rows per spmm wave (100000 % 8 == 0)

// round-to-nearest-even f32 -> bf16 helpers
__device__ __forceinline__ uint cvt_pk_bf16(float lo, float hi) {
    uint r;
    asm("v_cvt_pk_bf16_f32 %0, %1, %2" : "=v"(r) : "v"(lo), "v"(hi));
    return r;
}
// swizzled byte offset in a [rows][128] bf16 LDS tile (T2)
__device__ __forceinline__ int swz(int row, int k) {
    return (row * 256 + k * 2) ^ ((row & 7) << 4);
}

// ---------------------------------------------------------------------------
// Pre-kernel: Wt[n][k] = bf16(W[k][n]), PRE-SWIZZLED for flat LDS staging.
// ---------------------------------------------------------------------------
__global__ __launch_bounds__(256) void build_wt(const float* __restrict__ W,
                                                ushort* __restrict__ Wt) {
    const int sid = blockIdx.x * 256 + threadIdx.x;   // 4096 slots
    const int n = sid & 127, k0 = (sid >> 7) * 4;
    const float w0 = W[(k0 + 0) * FD + n];
    const float w1 = W[(k0 + 1) * FD + n];
    const float w2 = W[(k0 + 2) * FD + n];
    const float w3 = W[(k0 + 3) * FD + n];
    u32x2 p;
    p.x = cvt_pk_bf16(w0, w1);
    p.y = cvt_pk_bf16(w2, w3);
    *(u32x2*)((char*)Wt + swz(n, k0)) = p;
}

// ---------------------------------------------------------------------------
// row_ptr[r] = lower_bound(edge_row, r)
// ---------------------------------------------------------------------------
__global__ __launch_bounds__(256) void build_rowptr(const int* __restrict__ rows,
                                                    int* __restrict__ ptr) {
    const int r = blockIdx.x * 256 + threadIdx.x;
    if (r > NNODES) return;
    int lo = 0, hi = NEDGES;
    while (lo < hi) {
        const int mid = (lo + hi) >> 1;
        const bool lt = rows[mid] < r;
        lo = lt ? mid + 1 : lo;
        hi = lt ? hi : mid;
    }
    ptr[r] = lo;
}

// ---------------------------------------------------------------------------
// GEMM: S = X @ W via bf16 MFMA, then per-row symmetric int8 quantization:
//   scale[row] = rowmax/127 ; S8[row][f] = round(acc/scale) + 128  (uint8)
// 64x128 tile/block, 4 waves, 16x16x32 bf16 MFMA, swizzled LDS.
// ---------------------------------------------------------------------------
__global__ __launch_bounds__(256) void gemm_mfma_q8(const float* __restrict__ X,
                                                    const ushort* __restrict__ Wt,
                                                    uchar* __restrict__ S8,
                                                    float* __restrict__ scale) {
    __shared__ ushort As[BM * FD];   // 16 KB, swizzled (reused as u8 in epilogue)
    __shared__ ushort Bs[FD * FD];   // 32 KB, swizzled (flat copy of Wt)
    const int tid = threadIdx.x;
    const int row0 = blockIdx.x * BM;

    #pragma unroll
    for (int it = 0; it < 8; ++it) {
        const int idx = tid + it * 256;            // [0,2048)
        const int r = idx >> 5, k0 = (idx & 31) * 4;
        const int grow = min(row0 + r, NNODES - 1);
        const float4 g = *(const float4*)&X[grow * FD + k0];
        u32x2 p;
        p.x = cvt_pk_bf16(g.x, g.y);
        p.y = cvt_pk_bf16(g.z, g.w);
        *(u32x2*)((char*)As + swz(r, k0)) = p;
    }
    #pragma unroll
    for (int it = 0; it < 8; ++it) {
        const int b = (tid + it * 256) * 16;
        *(u32x4*)((char*)Bs + b) = *(const u32x4*)((const char*)Wt + b);
    }
    __syncthreads();

    const int lane = tid & 63, wv = tid >> 6;
    const int l15 = lane & 15, kg = lane >> 4;
    const int arow = wv * 16 + l15;

    f32x4 acc[8];
    #pragma unroll
    for (int i = 0; i < 8; ++i) acc[i] = (f32x4)0.f;

    #pragma unroll
    for (int ks = 0; ks < 4; ++ks) {
        const int k0 = ks * 32 + kg * 8;
        const u32x4 a = *(const u32x4*)((const char*)As + swz(arow, k0));
        #pragma unroll
        for (int nf = 0; nf < 8; ++nf) {
            const u32x4 b = *(const u32x4*)((const char*)Bs + swz(nf * 16 + l15, k0));
            asm volatile("v_mfma_f32_16x16x32_bf16 %0, %1, %2, %0"
                         : "+v"(acc[nf]) : "v"(a), "v"(b));
        }
    }
    asm volatile("s_nop 7\ns_nop 7\ns_nop 7");   // MFMA -> VALU hazard guard

    // ---- epilogue: per-row int8 quantization, LDS-transposed store ----
    __syncthreads();                 // everyone done reading As before reuse
    uchar* As8 = (uchar*)As;         // 64 x 128 u8 = 8 KB

    #pragma unroll
    for (int r = 0; r < 4; ++r) {
        float m = 0.f;
        #pragma unroll
        for (int nf = 0; nf < 8; ++nf) m = fmaxf(m, fabsf(acc[nf][r]));
        m = fmaxf(m, __shfl_xor(m, 1));
        m = fmaxf(m, __shfl_xor(m, 2));
        m = fmaxf(m, __shfl_xor(m, 4));
        m = fmaxf(m, __shfl_xor(m, 8));
        m = fmaxf(m, 1e-20f);
        const int lrow = wv * 16 + kg * 4 + r;         // C/D row map
        if (l15 == 0) scale[row0 + lrow] = m * (1.f / 127.f);
        const float inv = 127.f / m;
        #pragma unroll
        for (int nf = 0; nf < 8; ++nf) {
            const int q = (int)rintf(acc[nf][r] * inv) + 128;   // [1,255]
            As8[lrow * FD + nf * 16 + l15] = (uchar)q;
        }
    }
    __syncthreads();
    #pragma unroll
    for (int it = 0; it < 2; ++it) {
        const int o = (tid + it * 256) * 16;               // 8 KB block
        *(u32x4*)(S8 + (size_t)row0 * FD + o) = *(const u32x4*)(As8 + o);
    }
}

// ---------------------------------------------------------------------------
// VS[e] = edge_val[e] * scale[edge_col[e]]  (per-edge dequant premultiply)
// ---------------------------------------------------------------------------
__global__ __launch_bounds__(256) void build_vs(const int* __restrict__ ecol,
                                                const float* __restrict__ eval_,
                                                const float* __restrict__ scale,
                                                float* __restrict__ VS) {
    const int i = blockIdx.x * 256 + threadIdx.x;
    if (i < NEDGES) VS[i] = eval_[i] * scale[ecol[i]];
}

// ---------------------------------------------------------------------------
// SpMM: one wave owns RPW=8 consecutive rows = one contiguous edge range.
// Lane owns 2 features (one ushort = 2 bytes of S8 per gather; 64 lanes =
// 128 B fully-coalesced row read). 8-edge batches: all 8 gathers issued
// BEFORE the per-edge accumulate/flush logic (uniform branches only).
// Flush on row change: out = Svs_u - 128*Svs + bias, direct float2 store.
// ---------------------------------------------------------------------------
__global__ __launch_bounds__(256) void spmm_q8(const int* __restrict__ rptr,
                                               const int* __restrict__ erow,
                                               const int* __restrict__ ecol,
                                               const float* __restrict__ VS,
                                               const uchar* __restrict__ S8,
                                               const float* __restrict__ bias,
                                               float* __restrict__ out) {
    const int wv = (blockIdx.x * 256 + threadIdx.x) >> 6;   // 12500 waves exact
    const int r0 = wv * RPW;
    const int lane = threadIdx.x & 63;
    const float2 b2 = *(const float2*)&bias[lane * 2];

    const int E0 = __builtin_amdgcn_readfirstlane(rptr[r0]);
    const int E1 = __builtin_amdgcn_readfirstlane(rptr[r0 + RPW]);

    float a0 = 0.f, a1 = 0.f, sv = 0.f;
    int rcur = __builtin_amdgcn_readfirstlane(E0 < E1 ? erow[E0] : 0);

#define FLUSH() { float2 o;                                   \
    o.x = fmaf(-128.f, sv, a0) + b2.x;                        \
    o.y = fmaf(-128.f, sv, a1) + b2.y;                        \
    *(float2*)&out[(size_t)rcur * FD + lane * 2] = o;         \
    a0 = 0.f; a1 = 0.f; sv = 0.f; }

    for (int eb = E0 & ~7; eb < E1; eb += 8) {   // 32B-aligned meta batches
        int4 ra, rb, ca, cb; float4 va, vb;
        if (eb >= E0 && eb + 8 <= NEDGES) {      // common: aligned vector loads
            ra = *(const int4*)&erow[eb]; rb = *(const int4*)&erow[eb + 4];
            ca = *(const int4*)&ecol[eb]; cb = *(const int4*)&ecol[eb + 4];
            va = *(const float4*)&VS[eb]; vb = *(const float4*)&VS[eb + 4];
        } else {                                  // head/tail: clamped scalars
#define LDM(F, i) { const int e = min(max(eb + i, 0), NEDGES - 1);            \
            ((&F.x)[0]) = 0; }  /* placeholder to keep macro simple */
#undef LDM
#define LDE(dst, i) { const int e = min(max(eb + (i), 0), NEDGES - 1);        \
            dst = e; }
            int e0_, e1_, e2_, e3_, e4_, e5_, e6_, e7_;
            LDE(e0_, 0) LDE(e1_, 1) LDE(e2_, 2) LDE(e3_, 3)
            LDE(e4_, 4) LDE(e5_, 5) LDE(e6_, 6) LDE(e7_, 7)
            ra.x = erow[e0_]; ra.y = erow[e1_]; ra.z = erow[e2_]; ra.w = erow[e3_];
            rb.x = erow[e4_]; rb.y = erow[e5_]; rb.z = erow[e6_]; rb.w = erow[e7_];
            ca.x = ecol[e0_]; ca.y = ecol[e1_]; ca.z = ecol[e2_]; ca.w = ecol[e3_];
            cb.x = ecol[e4_]; cb.y = ecol[e5_]; cb.z = ecol[e6_]; cb.w = ecol[e7_];
            va.x = VS[e0_];   va.y = VS[e1_];   va.z = VS[e2_];   va.w = VS[e3_];
            vb.x = VS[e4_];   vb.y = VS[e5_];   vb.z = VS[e6_];   vb.w = VS[e7_];
#undef LDE
        }
        // issue all 8 gathers up front (independent, 128 B coalesced each)
#define GLD(c) (*(const ushort*)(S8 + ((uint)(c) << 7) + (lane << 1)))
        const ushort g0 = GLD(ca.x); const ushort g1 = GLD(ca.y);
        const ushort g2 = GLD(ca.z); const ushort g3 = GLD(ca.w);
        const ushort g4 = GLD(cb.x); const ushort g5 = GLD(cb.y);
        const ushort g6 = GLD(cb.z); const ushort g7 = GLD(cb.w);
#undef GLD
#define PROC(j, rj, vj, gj) {                                 \
        const int e_ = eb + (j);                              \
        if (e_ >= E0 && e_ < E1) {                            \
            if (rj != rcur) { FLUSH(); rcur = rj; }           \
            a0 = fmaf(vj, (float)(gj & 0xff), a0);            \
            a1 = fmaf(vj, (float)(gj >> 8), a1);              \
            sv += vj;                                         \
        } }
        PROC(0, ra.x, va.x, g0) PROC(1, ra.y, va.y, g1)
        PROC(2, ra.z, va.z, g2) PROC(3, ra.w, va.w, g3)
        PROC(4, rb.x, vb.x, g4) PROC(5, rb.y, vb.y, g5)
        PROC(6, rb.z, vb.z, g6) PROC(7, rb.w, vb.w, g7)
#undef PROC
    }
    if (E0 < E1) FLUSH();
#undef FLUSH

    // bias-only output for empty rows (P ~ 1e-7 per row, but must be correct)
    const int rl = r0 + min(lane, RPW);
    const int pa = rptr[rl], pb = rptr[min(rl + 1, NNODES)];
    const unsigned long long mask =
        __ballot(lane < RPW && pa == pb);
    if (mask) {
        for (int i = 0; i < RPW; ++i)
            if ((mask >> i) & 1)
                *(float2*)&out[(size_t)(r0 + i) * FD + lane * 2] = b2;
    }
}

// ---------------------------------------------------------------------------
extern "C" void kernel_launch(void* const* d_in, const int* in_sizes, int n_in,
                              void* d_out, int out_size, void* d_ws, size_t ws_size,
                              hipStream_t stream) {
    const float* X    = (const float*)d_in[0];
    const int*   erow = (const int*)d_in[1];
    const int*   ecol = (const int*)d_in[2];
    const float* eval_= (const float*)d_in[3];
    const float* W    = (const float*)d_in[4];
    const float* bias = (const float*)d_in[5];
    float* out = (float*)d_out;

    uchar* S8    = (uchar*)d_ws;                               // 12.8 MB
    float* scale = (float*)((char*)d_ws + 13u * 1024 * 1024);  // 400 KB
    int*   rpt   = (int*)((char*)d_ws + 14u * 1024 * 1024);    // 400 KB
    float* VS    = (float*)((char*)d_ws + 15u * 1024 * 1024);  // 6.4 MB
    ushort* Wt   = (ushort*)((char*)d_ws + 22u * 1024 * 1024); // 32 KB

    build_wt<<<16, 256, 0, stream>>>(W, Wt);
    build_rowptr<<<(NNODES + 256) / 256, 256, 0, stream>>>(erow, rpt);
    gemm_mfma_q8<<<NPAD / BM, 256, 0, stream>>>(X, Wt, S8, scale);   // 1563 blocks
    build_vs<<<(NEDGES + 255) / 256, 256, 0, stream>>>(ecol, eval_, scale, VS);
    spmm_q8<<<NNODES / RPW / 4, 256, 0, stream>>>(rpt, erow, ecol, VS, S8, bias, out);
}

// Round 6
// 88.882 us; speedup vs baseline: 2.7900x; 1.3930x over previous
//
#include <hip/hip_runtime.h>

typedef unsigned int uint;
typedef unsigned short ushort;
typedef unsigned char uchar;
typedef unsigned long long ull;
typedef __attribute__((ext_vector_type(4))) float f32x4;
typedef __attribute__((ext_vector_type(4))) uint u32x4;
typedef __attribute__((ext_vector_type(2))) uint u32x2;

#define NNODES 100000
#define NPAD   100032
#define NEDGES 1600000
#define FD 128
#define BM 64
#define RPW 10                 // rows per spmm wave; 100000/10 = 10000 waves

__device__ __forceinline__ uint cvt_pk_bf16(float lo, float hi) {
    uint r;
    asm("v_cvt_pk_bf16_f32 %0, %1, %2" : "=v"(r) : "v"(lo), "v"(hi));
    return r;
}
__device__ __forceinline__ int swz(int row, int k) {
    return (row * 256 + k * 2) ^ ((row & 7) << 4);
}

// ---------------------------------------------------------------------------
// Wt[n][k] = bf16(W[k][n]), PRE-SWIZZLED for flat LDS staging.
// ---------------------------------------------------------------------------
__global__ __launch_bounds__(256) void build_wt(const float* __restrict__ W,
                                                ushort* __restrict__ Wt) {
    const int sid = blockIdx.x * 256 + threadIdx.x;
    const int n = sid & 127, k0 = (sid >> 7) * 4;
    const float w0 = W[(k0 + 0) * FD + n];
    const float w1 = W[(k0 + 1) * FD + n];
    const float w2 = W[(k0 + 2) * FD + n];
    const float w3 = W[(k0 + 3) * FD + n];
    u32x2 p;
    p.x = cvt_pk_bf16(w0, w1);
    p.y = cvt_pk_bf16(w2, w3);
    *(u32x2*)((char*)Wt + swz(n, k0)) = p;
}

// ---------------------------------------------------------------------------
// row_ptr[r] = lower_bound(edge_row, r)
// ---------------------------------------------------------------------------
__global__ __launch_bounds__(256) void build_rowptr(const int* __restrict__ rows,
                                                    int* __restrict__ ptr) {
    const int r = blockIdx.x * 256 + threadIdx.x;
    if (r > NNODES) return;
    int lo = 0, hi = NEDGES;
    while (lo < hi) {
        const int mid = (lo + hi) >> 1;
        const bool lt = rows[mid] < r;
        lo = lt ? mid + 1 : lo;
        hi = lt ? hi : mid;
    }
    ptr[r] = lo;
}

// ---------------------------------------------------------------------------
// GEMM: S = X @ W via bf16 MFMA + per-row symmetric int8 quant (biased u8).
// ---------------------------------------------------------------------------
__global__ __launch_bounds__(256) void gemm_mfma_q8(const float* __restrict__ X,
                                                    const ushort* __restrict__ Wt,
                                                    uchar* __restrict__ S8,
                                                    float* __restrict__ scale) {
    __shared__ ushort As[BM * FD];   // 16 KB, swizzled; reused as u8 in epilogue
    __shared__ ushort Bs[FD * FD];   // 32 KB, swizzled
    const int tid = threadIdx.x;
    const int row0 = blockIdx.x * BM;

    #pragma unroll
    for (int it = 0; it < 8; ++it) {
        const int idx = tid + it * 256;
        const int r = idx >> 5, k0 = (idx & 31) * 4;
        const int grow = min(row0 + r, NNODES - 1);
        const float4 g = *(const float4*)&X[grow * FD + k0];
        u32x2 p;
        p.x = cvt_pk_bf16(g.x, g.y);
        p.y = cvt_pk_bf16(g.z, g.w);
        *(u32x2*)((char*)As + swz(r, k0)) = p;
    }
    #pragma unroll
    for (int it = 0; it < 8; ++it) {
        const int b = (tid + it * 256) * 16;
        *(u32x4*)((char*)Bs + b) = *(const u32x4*)((const char*)Wt + b);
    }
    __syncthreads();

    const int lane = tid & 63, wv = tid >> 6;
    const int l15 = lane & 15, kg = lane >> 4;
    const int arow = wv * 16 + l15;

    f32x4 acc[8];
    #pragma unroll
    for (int i = 0; i < 8; ++i) acc[i] = (f32x4)0.f;

    #pragma unroll
    for (int ks = 0; ks < 4; ++ks) {
        const int k0 = ks * 32 + kg * 8;
        const u32x4 a = *(const u32x4*)((const char*)As + swz(arow, k0));
        #pragma unroll
        for (int nf = 0; nf < 8; ++nf) {
            const u32x4 b = *(const u32x4*)((const char*)Bs + swz(nf * 16 + l15, k0));
            asm volatile("v_mfma_f32_16x16x32_bf16 %0, %1, %2, %0"
                         : "+v"(acc[nf]) : "v"(a), "v"(b));
        }
    }
    asm volatile("s_nop 7\ns_nop 7\ns_nop 7");

    __syncthreads();
    uchar* As8 = (uchar*)As;

    #pragma unroll
    for (int r = 0; r < 4; ++r) {
        float m = 0.f;
        #pragma unroll
        for (int nf = 0; nf < 8; ++nf) m = fmaxf(m, fabsf(acc[nf][r]));
        m = fmaxf(m, __shfl_xor(m, 1));
        m = fmaxf(m, __shfl_xor(m, 2));
        m = fmaxf(m, __shfl_xor(m, 4));
        m = fmaxf(m, __shfl_xor(m, 8));
        m = fmaxf(m, 1e-20f);
        const int lrow = wv * 16 + kg * 4 + r;
        if (l15 == 0) scale[row0 + lrow] = m * (1.f / 127.f);
        const float inv = 127.f / m;
        #pragma unroll
        for (int nf = 0; nf < 8; ++nf) {
            const int q = (int)rintf(acc[nf][r] * inv) + 128;   // [1,255]
            As8[lrow * FD + nf * 16 + l15] = (uchar)q;
        }
    }
    __syncthreads();
    #pragma unroll
    for (int it = 0; it < 2; ++it) {
        const int o = (tid + it * 256) * 16;
        *(u32x4*)(S8 + (size_t)row0 * FD + o) = *(const u32x4*)(As8 + o);
    }
}

// ---------------------------------------------------------------------------
// VS[e] = edge_val[e] * scale[edge_col[e]]
// ---------------------------------------------------------------------------
__global__ __launch_bounds__(256) void build_vs(const int* __restrict__ ecol,
                                                const float* __restrict__ eval_,
                                                const float* __restrict__ scale,
                                                float* __restrict__ VS) {
    const int i = blockIdx.x * 256 + threadIdx.x;
    if (i < NEDGES) VS[i] = eval_[i] * scale[ecol[i]];
}

// ---------------------------------------------------------------------------
// SpMM, software-pipelined. Wave owns RPW=10 rows = one contiguous edge
// range. Per 8-edge batch: ONE combined meta load (lanes 0-7 cols, 8-15 VS,
// 16-23 rows), readlane -> SGPR scalars, 8 ushort gathers (full 128B int8
// row per wave-instr). Iteration b: issue gathers(b+1) + meta(b+2), then
// PROC batch b -> every load has >= 1 iteration of latency slack.
// ---------------------------------------------------------------------------
__global__ __launch_bounds__(256, 8) void spmm_pipe(const int* __restrict__ rptr,
                                                    const int* __restrict__ erow,
                                                    const int* __restrict__ ecol,
                                                    const float* __restrict__ VS,
                                                    const uchar* __restrict__ S8,
                                                    const float* __restrict__ bias,
                                                    float* __restrict__ out) {
    const int wv = (blockIdx.x * 256 + threadIdx.x) >> 6;   // 10000 waves exact
    const int lane = threadIdx.x & 63;
    const int r0 = wv * RPW;
    const float2 b2 = *(const float2*)&bias[lane * 2];

    const int E0 = __builtin_amdgcn_readfirstlane(rptr[r0]);
    const int E1 = __builtin_amdgcn_readfirstlane(rptr[r0 + RPW]);

    // per-lane combined meta base: lanes 0-7 cols, 8-15 VS, 16-23 rows
    const int sl = lane & 7;
    const uint* mbase = (lane < 8) ? (const uint*)ecol
                      : (lane < 16) ? (const uint*)VS
                                    : (const uint*)erow;

    float a0 = 0.f, a1 = 0.f, sv = 0.f;

    if (E0 < E1) {
        const int nb = (E1 - E0 + 7) >> 3;

#define LOADMETA(dst, b) { \
        const int idx_ = min(E0 + (b) * 8 + sl, NEDGES - 1); \
        dst = mbase[idx_]; }

#define GATHER(G, m) { \
        _Pragma("unroll") for (int j = 0; j < 8; ++j) { \
            const int c_ = __builtin_amdgcn_readlane((int)(m), j); \
            G[j] = (uint)*(const ushort*)(S8 + (((uint)c_) << 7) + (lane << 1)); } }

#define EXTRACT(R, V, m) { \
        _Pragma("unroll") for (int j = 0; j < 8; ++j) { \
            V[j] = __int_as_float(__builtin_amdgcn_readlane((int)(m), 8 + j)); \
            R[j] = __builtin_amdgcn_readlane((int)(m), 16 + j); } }

#define FLUSH() { float2 o_; \
        o_.x = fmaf(-128.f, sv, a0) + b2.x; \
        o_.y = fmaf(-128.f, sv, a1) + b2.y; \
        *(float2*)&out[(size_t)rcur * FD + (lane << 1)] = o_; \
        a0 = 0.f; a1 = 0.f; sv = 0.f; }

#define PROC1(G, R, V, j) { \
        if (R[j] != rcur) { FLUSH(); rcur = R[j]; } \
        const float lo_ = (float)(G[j] & 0xffu); \
        const float hi_ = (float)((G[j] >> 8) & 0xffu); \
        a0 = fmaf(V[j], lo_, a0); \
        a1 = fmaf(V[j], hi_, a1); \
        sv += V[j]; }

#define PROC_FAST(G, R, V) { \
        _Pragma("unroll") for (int j = 0; j < 8; ++j) { PROC1(G, R, V, j) } }

#define PROC_LAST(G, R, V, eb) { \
        _Pragma("unroll") for (int j = 0; j < 8; ++j) { \
            if ((eb) + j < E1) { PROC1(G, R, V, j) } } }

#define BODY(MC, MN, GC, GN, RC, VC, RN, VN, b) { \
        if ((b) + 1 < nb) { GATHER(GN, MN); EXTRACT(RN, VN, MN); } \
        if ((b) + 2 < nb) { LOADMETA(MC, (b) + 2); } \
        if ((b) == nb - 1) { PROC_LAST(GC, RC, VC, E0 + (b) * 8) } \
        else { PROC_FAST(GC, RC, VC) } }

        uint mA, mB = 0;
        uint gA[8], gB[8];
        int rA[8], rB[8];
        float vA[8], vB[8];

        LOADMETA(mA, 0);
        GATHER(gA, mA);
        EXTRACT(rA, vA, mA);
        int rcur = rA[0];
        if (nb > 1) LOADMETA(mB, 1);

        int b = 0;
        while (true) {
            BODY(mA, mB, gA, gB, rA, vA, rB, vB, b);
            if (++b >= nb) break;
            BODY(mB, mA, gB, gA, rB, vB, rA, vA, b);
            if (++b >= nb) break;
        }
        FLUSH();

#undef BODY
#undef PROC_LAST
#undef PROC_FAST
#undef PROC1
#undef FLUSH
#undef EXTRACT
#undef GATHER
#undef LOADMETA
    }

    // bias-only output for empty rows (rare but must be correct)
    const int rl = r0 + ((lane < RPW) ? lane : RPW - 1);
    const bool em = (lane < RPW) && (rptr[rl] == rptr[rl + 1]);
    ull mask = __ballot(em);
    while (mask) {
        const int i = __ffsll((ull)mask) - 1;
        mask &= mask - 1;
        *(float2*)&out[(size_t)(r0 + i) * FD + lane * 2] = b2;
    }
}

// ---------------------------------------------------------------------------
extern "C" void kernel_launch(void* const* d_in, const int* in_sizes, int n_in,
                              void* d_out, int out_size, void* d_ws, size_t ws_size,
                              hipStream_t stream) {
    const float* X    = (const float*)d_in[0];
    const int*   erow = (const int*)d_in[1];
    const int*   ecol = (const int*)d_in[2];
    const float* eval_= (const float*)d_in[3];
    const float* W    = (const float*)d_in[4];
    const float* bias = (const float*)d_in[5];
    float* out = (float*)d_out;

    uchar* S8    = (uchar*)d_ws;                               // 12.8 MB
    float* scale = (float*)((char*)d_ws + 13u * 1024 * 1024);  // 400 KB
    int*   rpt   = (int*)((char*)d_ws + 14u * 1024 * 1024);    // 400 KB
    float* VS    = (float*)((char*)d_ws + 15u * 1024 * 1024);  // 6.4 MB
    ushort* Wt   = (ushort*)((char*)d_ws + 22u * 1024 * 1024); // 32 KB

    build_wt<<<16, 256, 0, stream>>>(W, Wt);
    build_rowptr<<<(NNODES + 256) / 256, 256, 0, stream>>>(erow, rpt);
    gemm_mfma_q8<<<NPAD / BM, 256, 0, stream>>>(X, Wt, S8, scale);
    build_vs<<<(NEDGES + 255) / 256, 256, 0, stream>>>(ecol, eval_, scale, VS);
    spmm_pipe<<<NNODES / RPW / 4, 256, 0, stream>>>(rpt, erow, ecol, VS, S8, bias, out);
}

// Round 7
// 86.961 us; speedup vs baseline: 2.8516x; 1.0221x over previous
//
#include <hip/hip_runtime.h>

typedef unsigned int uint;
typedef unsigned short ushort;
typedef unsigned char uchar;
typedef unsigned long long ull;
typedef __attribute__((ext_vector_type(4))) float f32x4;
typedef __attribute__((ext_vector_type(4))) uint u32x4;
typedef __attribute__((ext_vector_type(2))) uint u32x2;

#define NNODES 100000
#define NPAD   100032
#define NEDGES 1600000
#define FD 128
#define BM 64

__device__ __forceinline__ uint cvt_pk_bf16(float lo, float hi) {
    uint r;
    asm("v_cvt_pk_bf16_f32 %0, %1, %2" : "=v"(r) : "v"(lo), "v"(hi));
    return r;
}
__device__ __forceinline__ int swz(int row, int k) {
    return (row * 256 + k * 2) ^ ((row & 7) << 4);
}

// ---------------------------------------------------------------------------
// prep: blocks 0-15 build Wt (bf16(W^T), pre-swizzled); blocks 16+ build
// row_ptr[r] = lower_bound(edge_row, r). Merged to save a launch.
// ---------------------------------------------------------------------------
__global__ __launch_bounds__(256) void prep(const float* __restrict__ W,
                                            ushort* __restrict__ Wt,
                                            const int* __restrict__ rows,
                                            int* __restrict__ ptr) {
    const int bid = blockIdx.x;
    if (bid < 16) {
        const int sid = bid * 256 + threadIdx.x;   // 4096 slots
        const int n = sid & 127, k0 = (sid >> 7) * 4;
        const float w0 = W[(k0 + 0) * FD + n];
        const float w1 = W[(k0 + 1) * FD + n];
        const float w2 = W[(k0 + 2) * FD + n];
        const float w3 = W[(k0 + 3) * FD + n];
        u32x2 p;
        p.x = cvt_pk_bf16(w0, w1);
        p.y = cvt_pk_bf16(w2, w3);
        *(u32x2*)((char*)Wt + swz(n, k0)) = p;
    } else {
        const int r = (bid - 16) * 256 + threadIdx.x;
        if (r > NNODES) return;
        int lo = 0, hi = NEDGES;
        while (lo < hi) {
            const int mid = (lo + hi) >> 1;
            const bool lt = rows[mid] < r;
            lo = lt ? mid + 1 : lo;
            hi = lt ? hi : mid;
        }
        ptr[r] = lo;
    }
}

// ---------------------------------------------------------------------------
// GEMM: S = X @ W via bf16 MFMA + per-row symmetric int8 quant (biased u8).
// ---------------------------------------------------------------------------
__global__ __launch_bounds__(256) void gemm_mfma_q8(const float* __restrict__ X,
                                                    const ushort* __restrict__ Wt,
                                                    uchar* __restrict__ S8,
                                                    float* __restrict__ scale) {
    __shared__ ushort As[BM * FD];   // 16 KB, swizzled; reused as u8 in epilogue
    __shared__ ushort Bs[FD * FD];   // 32 KB, swizzled
    const int tid = threadIdx.x;
    const int row0 = blockIdx.x * BM;

    #pragma unroll
    for (int it = 0; it < 8; ++it) {
        const int idx = tid + it * 256;
        const int r = idx >> 5, k0 = (idx & 31) * 4;
        const int grow = min(row0 + r, NNODES - 1);
        const float4 g = *(const float4*)&X[grow * FD + k0];
        u32x2 p;
        p.x = cvt_pk_bf16(g.x, g.y);
        p.y = cvt_pk_bf16(g.z, g.w);
        *(u32x2*)((char*)As + swz(r, k0)) = p;
    }
    #pragma unroll
    for (int it = 0; it < 8; ++it) {
        const int b = (tid + it * 256) * 16;
        *(u32x4*)((char*)Bs + b) = *(const u32x4*)((const char*)Wt + b);
    }
    __syncthreads();

    const int lane = tid & 63, wv = tid >> 6;
    const int l15 = lane & 15, kg = lane >> 4;
    const int arow = wv * 16 + l15;

    f32x4 acc[8];
    #pragma unroll
    for (int i = 0; i < 8; ++i) acc[i] = (f32x4)0.f;

    #pragma unroll
    for (int ks = 0; ks < 4; ++ks) {
        const int k0 = ks * 32 + kg * 8;
        const u32x4 a = *(const u32x4*)((const char*)As + swz(arow, k0));
        #pragma unroll
        for (int nf = 0; nf < 8; ++nf) {
            const u32x4 b = *(const u32x4*)((const char*)Bs + swz(nf * 16 + l15, k0));
            asm volatile("v_mfma_f32_16x16x32_bf16 %0, %1, %2, %0"
                         : "+v"(acc[nf]) : "v"(a), "v"(b));
        }
    }
    asm volatile("s_nop 7\ns_nop 7\ns_nop 7");

    __syncthreads();
    uchar* As8 = (uchar*)As;

    #pragma unroll
    for (int r = 0; r < 4; ++r) {
        float m = 0.f;
        #pragma unroll
        for (int nf = 0; nf < 8; ++nf) m = fmaxf(m, fabsf(acc[nf][r]));
        m = fmaxf(m, __shfl_xor(m, 1));
        m = fmaxf(m, __shfl_xor(m, 2));
        m = fmaxf(m, __shfl_xor(m, 4));
        m = fmaxf(m, __shfl_xor(m, 8));
        m = fmaxf(m, 1e-20f);
        const int lrow = wv * 16 + kg * 4 + r;
        if (l15 == 0) scale[row0 + lrow] = m * (1.f / 127.f);
        const float inv = 127.f / m;
        #pragma unroll
        for (int nf = 0; nf < 8; ++nf) {
            const int q = (int)rintf(acc[nf][r] * inv) + 128;   // [1,255]
            As8[lrow * FD + nf * 16 + l15] = (uchar)q;
        }
    }
    __syncthreads();
    #pragma unroll
    for (int it = 0; it < 2; ++it) {
        const int o = (tid + it * 256) * 16;
        *(u32x4*)(S8 + (size_t)row0 * FD + o) = *(const u32x4*)(As8 + o);
    }
}

// ---------------------------------------------------------------------------
// VS[e] = edge_val[e] * scale[edge_col[e]]
// ---------------------------------------------------------------------------
__global__ __launch_bounds__(256) void build_vs(const int* __restrict__ ecol,
                                                const float* __restrict__ eval_,
                                                const float* __restrict__ scale,
                                                float* __restrict__ VS) {
    const int i = blockIdx.x * 256 + threadIdx.x;
    if (i < NEDGES) VS[i] = eval_[i] * scale[ecol[i]];
}

// ---------------------------------------------------------------------------
// SpMM: ONE WAVE PER ROW. No row-change logic, no erow stream, exactly one
// float2 store per row (empty rows -> bias automatically). 16-edge chunks,
// A/B rotated: gathers for chunk c+1 and meta for chunk c+2 issued before
// PROCessing chunk c -> 16+ gathers in flight per wave. Tail edges handled
// branch-free: meta index clamped to the row's last edge (L1-hit dups) and
// vs zeroed via uniform s_cselect.
// Meta layout: lanes 0-15 read ecol, lanes 16-31 read VS (one load/chunk).
// ---------------------------------------------------------------------------
__global__ __launch_bounds__(256, 8) void spmm_row(const int* __restrict__ rptr,
                                                   const int* __restrict__ ecol,
                                                   const float* __restrict__ VS,
                                                   const uchar* __restrict__ S8,
                                                   const float* __restrict__ bias,
                                                   float* __restrict__ out) {
    const int row = (blockIdx.x * 256 + threadIdx.x) >> 6;   // 100000 waves exact
    const int lane = threadIdx.x & 63;
    const float2 b2 = *(const float2*)&bias[lane * 2];

    const int E0 = __builtin_amdgcn_readfirstlane(rptr[row]);
    const int E1 = __builtin_amdgcn_readfirstlane(rptr[row + 1]);

    const int ml = lane & 15;
    const uint* mb = (lane & 16) ? (const uint*)VS : (const uint*)ecol;
    const uint voff = (uint)lane << 1;

    float a00 = 0.f, a01 = 0.f, a10 = 0.f, a11 = 0.f;
    float sv0 = 0.f, sv1 = 0.f;

    const int nc = (E1 - E0 + 15) >> 4;
    if (nc > 0) {

#define LOADMETA(m, c) { \
        const int i_ = min(E0 + (c) * 16 + ml, E1 - 1); \
        m = mb[i_]; }

#define STAGE(G, V, m, c) { \
        _Pragma("unroll") for (int j = 0; j < 16; ++j) { \
            const uint cj = (uint)__builtin_amdgcn_readlane((int)(m), j); \
            G[j] = (uint)*(const ushort*)(S8 + ((size_t)cj << 7) + voff); \
            const uint uv = (uint)__builtin_amdgcn_readlane((int)(m), 16 + j); \
            const uint uz = (E0 + (c) * 16 + j < E1) ? uv : 0u;  /* uniform */ \
            V[j] = __uint_as_float(uz); } }

#define PROC(G, V) { \
        _Pragma("unroll") for (int j = 0; j < 16; ++j) { \
            const float lo_ = (float)(G[j] & 0xffu); \
            const float hi_ = (float)((G[j] >> 8) & 0xffu); \
            if (j & 1) { a10 = fmaf(V[j], lo_, a10); \
                         a11 = fmaf(V[j], hi_, a11); sv1 += V[j]; } \
            else       { a00 = fmaf(V[j], lo_, a00); \
                         a01 = fmaf(V[j], hi_, a01); sv0 += V[j]; } } }

        uint mA, mB = 0;
        uint gA[16], gB[16];
        float vA[16], vB[16];

        LOADMETA(mA, 0);
        STAGE(gA, vA, mA, 0);
        if (nc > 1) LOADMETA(mB, 1);

        int c = 0;
        while (true) {
            if (c + 1 < nc) STAGE(gB, vB, mB, c + 1);
            if (c + 2 < nc) LOADMETA(mA, c + 2);
            PROC(gA, vA);
            if (++c >= nc) break;
            if (c + 1 < nc) STAGE(gA, vA, mA, c + 1);
            if (c + 2 < nc) LOADMETA(mB, c + 2);
            PROC(gB, vB);
            if (++c >= nc) break;
        }
#undef PROC
#undef STAGE
#undef LOADMETA
    }

    const float sv = sv0 + sv1;
    float2 o;
    o.x = fmaf(-128.f, sv, a00 + a10) + b2.x;
    o.y = fmaf(-128.f, sv, a01 + a11) + b2.y;
    *(float2*)&out[(size_t)row * FD + voff] = o;
}

// ---------------------------------------------------------------------------
extern "C" void kernel_launch(void* const* d_in, const int* in_sizes, int n_in,
                              void* d_out, int out_size, void* d_ws, size_t ws_size,
                              hipStream_t stream) {
    const float* X    = (const float*)d_in[0];
    const int*   erow = (const int*)d_in[1];
    const int*   ecol = (const int*)d_in[2];
    const float* eval_= (const float*)d_in[3];
    const float* W    = (const float*)d_in[4];
    const float* bias = (const float*)d_in[5];
    float* out = (float*)d_out;

    uchar* S8    = (uchar*)d_ws;                               // 12.8 MB
    float* scale = (float*)((char*)d_ws + 13u * 1024 * 1024);  // 400 KB
    int*   rpt   = (int*)((char*)d_ws + 14u * 1024 * 1024);    // 400 KB
    float* VS    = (float*)((char*)d_ws + 15u * 1024 * 1024);  // 6.4 MB
    ushort* Wt   = (ushort*)((char*)d_ws + 22u * 1024 * 1024); // 32 KB

    prep<<<16 + (NNODES + 256) / 256, 256, 0, stream>>>(W, Wt, erow, rpt);
    gemm_mfma_q8<<<NPAD / BM, 256, 0, stream>>>(X, Wt, S8, scale);
    build_vs<<<(NEDGES + 255) / 256, 256, 0, stream>>>(ecol, eval_, scale, VS);
    spmm_row<<<NNODES / 4, 256, 0, stream>>>(rpt, ecol, VS, S8, bias, out);
}